// Round 11
// baseline (266.397 us; speedup 1.0000x reference)
//
#include <hip/hip_runtime.h>

#define N1 4096
#define N2 2048
#define PD 256
#define DZ 128
#define PD2 258
#define PD2P 264
#define FD 772
#define FDP 776
#define APN 272      // lmFT rows padded; row 258 = ones -> attr_sum
#define APLD 72
#define SPLITS 16

typedef short s8v __attribute__((ext_vector_type(8)));
typedef float f32x4 __attribute__((ext_vector_type(4)));

__device__ __forceinline__ short f2b(float f) {
    union { float f; unsigned u; } v; v.f = f;
    unsigned r = v.u + 0x7fffu + ((v.u >> 16) & 1u);
    return (short)(r >> 16);
}
__device__ __forceinline__ float sb2f(short s) {
    union { unsigned u; float f; } v;
    v.u = ((unsigned)(unsigned short)s) << 16;
    return v.f;
}

// ---------------------------------------------------------------- prep
// grid layout: [0,256) kk tiles | [256,320) qb tiles | [320,345) M=W2*W1 tiles
//              | [345, 345+6836) flat regions
#define GB_KK  0
#define GB_QB  256
#define GB_M   320
#define GB_FL  345
// flat regions (each multiple of 256):
constexpr int P0 = 524288;            // tgX -> outF / finalFb cols 0..255
constexpr int P1 = P0 + 99328;        // pqwb (772 -> 776 pad)
constexpr int P2 = P1 + 1114112;      // lmFTb transpose + router atomics
constexpr int P3 = P2 + 4096;         // delay: rou0/rou1/v2b + sumd atomic
constexpr int P4 = P3 + 8192;         // finalFb pad cols 772..775

__global__ __launch_bounds__(256) void prep(
    const float* __restrict__ lmX, const float* __restrict__ lmY,
    const float* __restrict__ tgX,
    const float* __restrict__ aqw, const float* __restrict__ aqb,
    const float* __restrict__ akw, const float* __restrict__ akb,
    const float* __restrict__ pkw, const float* __restrict__ pkb,
    const float* __restrict__ pqw,
    const float* __restrict__ w1w, const float* __restrict__ w2w,
    const float* __restrict__ lmd, const float* __restrict__ tgd,
    const float* __restrict__ g1, const float* __restrict__ g2,
    const float* __restrict__ g3, const float* __restrict__ al,
    const float* __restrict__ be,
    const float* __restrict__ pvw, const float* __restrict__ pvb,
    float* __restrict__ outF, short* __restrict__ finalFb,
    short* __restrict__ pqwb, short* __restrict__ lmFTb,
    float* __restrict__ rou0, float* __restrict__ rou1,
    float* __restrict__ v2b,
    float* __restrict__ r0acc, float* __restrict__ rp0acc,
    float* __restrict__ sumd,
    short* __restrict__ kk, short* __restrict__ qb,
    short* __restrict__ Mb)
{
    __shared__ __align__(16) short LDS[5120];
    const int bid = blockIdx.x, tid = threadIdx.x;
    const int lane = tid & 63, wv = tid >> 6;
    const int wm = wv >> 1, wn = wv & 1;
    const int lm = lane & 15, lq = lane >> 4;
    const f32x4 zero4 = {0.f, 0.f, 0.f, 0.f};
    const s8v zero8 = {0, 0, 0, 0, 0, 0, 0, 0};
    short* Als = LDS;
    short* Bls = LDS + 64 * 40;
    const int r = tid >> 2, cgp = tid & 3;

    if (bid < GB_QB) {                              // ---- kk tile
        int jt = bid;
        int row0 = (jt >> 2) * 64, col0 = (jt & 3) * 64;
        f32x4 acc[2][2] = {{zero4, zero4}, {zero4, zero4}};
        for (int k0 = 0; k0 < 256; k0 += 32) {
            int gk = k0 + cgp * 8;
            const float* ap = lmX + (size_t)(row0 + r) * PD + gk;
            int c = col0 + r;
            const float* bp = (c < 128) ? akw + (size_t)c * PD + gk
                                        : pkw + (size_t)(c - 128) * PD + gk;
            s8v va, vb;
#pragma unroll
            for (int q = 0; q < 8; ++q) { va[q] = f2b(ap[q]); vb[q] = f2b(bp[q]); }
            *(s8v*)(Als + r * 40 + cgp * 8) = va;
            *(s8v*)(Bls + r * 40 + cgp * 8) = vb;
            __syncthreads();
            s8v af[2], bf[2];
#pragma unroll
            for (int mt = 0; mt < 2; ++mt)
                af[mt] = *(const s8v*)(Als + (wm * 32 + mt * 16 + lm) * 40 + lq * 8);
#pragma unroll
            for (int nt = 0; nt < 2; ++nt)
                bf[nt] = *(const s8v*)(Bls + (wn * 32 + nt * 16 + lm) * 40 + lq * 8);
#pragma unroll
            for (int mt = 0; mt < 2; ++mt)
#pragma unroll
                for (int nt = 0; nt < 2; ++nt)
                    acc[mt][nt] = __builtin_amdgcn_mfma_f32_16x16x32_bf16(
                        af[mt], bf[nt], acc[mt][nt], 0, 0, 0);
            __syncthreads();
        }
#pragma unroll
        for (int mt = 0; mt < 2; ++mt)
#pragma unroll
            for (int nt = 0; nt < 2; ++nt) {
                int c = col0 + wn * 32 + nt * 16 + lm;
                float bv = (c < 128) ? akb[c] : pkb[c - 128];
#pragma unroll
                for (int i = 0; i < 4; ++i) {
                    int rr = row0 + wm * 32 + mt * 16 + lq * 4 + i;
                    kk[(size_t)rr * 256 + c] = f2b(acc[mt][nt][i] + bv);
                }
            }
        return;
    }
    if (bid < GB_M) {                               // ---- qb tile
        int jt = bid - GB_QB;
        int row0 = (jt >> 1) * 64, col0 = (jt & 1) * 64;
        f32x4 acc[2][2] = {{zero4, zero4}, {zero4, zero4}};
        for (int k0 = 0; k0 < 256; k0 += 32) {
            int gk = k0 + cgp * 8;
            const float* ap = tgX + (size_t)(row0 + r) * PD + gk;
            const float* bp = aqw + (size_t)(col0 + r) * PD + gk;
            s8v va, vb;
#pragma unroll
            for (int q = 0; q < 8; ++q) { va[q] = f2b(ap[q]); vb[q] = f2b(bp[q]); }
            *(s8v*)(Als + r * 40 + cgp * 8) = va;
            *(s8v*)(Bls + r * 40 + cgp * 8) = vb;
            __syncthreads();
            s8v af[2], bf[2];
#pragma unroll
            for (int mt = 0; mt < 2; ++mt)
                af[mt] = *(const s8v*)(Als + (wm * 32 + mt * 16 + lm) * 40 + lq * 8);
#pragma unroll
            for (int nt = 0; nt < 2; ++nt)
                bf[nt] = *(const s8v*)(Bls + (wn * 32 + nt * 16 + lm) * 40 + lq * 8);
#pragma unroll
            for (int mt = 0; mt < 2; ++mt)
#pragma unroll
                for (int nt = 0; nt < 2; ++nt)
                    acc[mt][nt] = __builtin_amdgcn_mfma_f32_16x16x32_bf16(
                        af[mt], bf[nt], acc[mt][nt], 0, 0, 0);
            __syncthreads();
        }
        const float INV_TEMP = 0.08838834764831845f;
#pragma unroll
        for (int mt = 0; mt < 2; ++mt)
#pragma unroll
            for (int nt = 0; nt < 2; ++nt) {
                int c = col0 + wn * 32 + nt * 16 + lm;
                float bv = aqb[c];
#pragma unroll
                for (int i = 0; i < 4; ++i) {
                    int rr = row0 + wm * 32 + mt * 16 + lq * 4 + i;
                    qb[(size_t)rr * DZ + c] = f2b(INV_TEMP * (acc[mt][nt][i] + bv));
                }
            }
        return;
    }
    if (bid < GB_FL) {                              // ---- M = W2*W1 tile
        int jm = bid - GB_M;
        int row0 = (jm / 5) * 64, col0 = (jm % 5) * 64;
        f32x4 acc[2][2] = {{zero4, zero4}, {zero4, zero4}};
        for (int k0 = 0; k0 < 264; k0 += 32) {
            int gk = k0 + cgp * 8;
            s8v va = zero8, vb = zero8;
            int arow = row0 + r, bcol = col0 + r;
#pragma unroll
            for (int q = 0; q < 8; ++q) {
                int kidx = gk + q;
                if (kidx < PD2) {
                    if (arow < PD2) va[q] = f2b(w2w[(size_t)arow * PD2 + kidx]);
                    if (bcol < PD2) vb[q] = f2b(w1w[(size_t)kidx * PD2 + bcol]);
                }
            }
            *(s8v*)(Als + r * 40 + cgp * 8) = va;
            *(s8v*)(Bls + r * 40 + cgp * 8) = vb;
            __syncthreads();
            s8v af[2], bf[2];
#pragma unroll
            for (int mt = 0; mt < 2; ++mt)
                af[mt] = *(const s8v*)(Als + (wm * 32 + mt * 16 + lm) * 40 + lq * 8);
#pragma unroll
            for (int nt = 0; nt < 2; ++nt)
                bf[nt] = *(const s8v*)(Bls + (wn * 32 + nt * 16 + lm) * 40 + lq * 8);
#pragma unroll
            for (int mt = 0; mt < 2; ++mt)
#pragma unroll
                for (int nt = 0; nt < 2; ++nt)
                    acc[mt][nt] = __builtin_amdgcn_mfma_f32_16x16x32_bf16(
                        af[mt], bf[nt], acc[mt][nt], 0, 0, 0);
            __syncthreads();
        }
#pragma unroll
        for (int mt = 0; mt < 2; ++mt)
#pragma unroll
            for (int nt = 0; nt < 2; ++nt) {
                int c = col0 + wn * 32 + nt * 16 + lm;
#pragma unroll
                for (int i = 0; i < 4; ++i) {
                    int rr = row0 + wm * 32 + mt * 16 + lq * 4 + i;
                    if (rr >= PD2 || c >= PD2P) continue;
                    Mb[(size_t)rr * PD2P + c] = (c < PD2) ? f2b(acc[mt][nt][i]) : (short)0;
                }
            }
        return;
    }
    // ---- flat regions
    int i = (bid - GB_FL) * 256 + tid;
    if (i < P0) {
        int rr = i >> 8, c = i & 255;
        float v = tgX[i];
        outF[(size_t)rr * FD + c] = v;
        finalFb[(size_t)rr * FDP + c] = f2b(v);
        return;
    }
    if (i < P1) {
        int j = i - P0; int rr = j / FDP, c = j - rr * FDP;
        pqwb[j] = (c < FD) ? f2b(pqw[(size_t)rr * FD + c]) : (short)0;
        return;
    }
    if (i < P2) {                                   // lmFTb transpose + router atomics
        int j = i - P1;
        int c = j >> 12, rr = j & (N1 - 1);         // c uniform per block
        float v = 0.f;
        if (c < PD) v = lmX[(size_t)rr * PD + c];
        else if (c < PD2) v = lmY[rr * 2 + (c - PD)];
        else if (c == PD2) v = 1.0f;
        lmFTb[j] = f2b(v);
        if (c < PD2) {
            float a = al[0], b = be[0];
            float d = __expf(-g1[0] * (a * lmd[rr] + b));
            float* red1 = (float*)LDS;
            float* red2 = red1 + 256;
            red1[tid] = v; red2[tid] = d * v; __syncthreads();
            for (int o = 128; o > 0; o >>= 1) {
                if (tid < o) { red1[tid] += red1[tid + o]; red2[tid] += red2[tid + o]; }
                __syncthreads();
            }
            if (tid == 0) {
                atomicAdd(&r0acc[c], red1[0]);
                atomicAdd(&rp0acc[c], red2[0]);
            }
        }
        return;
    }
    if (i < P3) {                                   // delay / v2 / sumd
        int j = i - P2;                             // j in [0,4096)
        float a = al[0], b = be[0];
        float d = __expf(-g1[0] * (a * lmd[j] + b));
        float y0 = lmY[2 * j], y1 = lmY[2 * j + 1];
        v2b[2 * j]     = pvw[0] * y0 + pvw[1] * y1 + pvb[0];
        v2b[2 * j + 1] = pvw[2] * y0 + pvw[3] * y1 + pvb[1];
        if (j < N2) {
            float t = a * tgd[j] + b;
            rou0[j] = __expf(-g2[0] * t);
            rou1[j] = __expf(-g3[0] * t);
        }
        float* red1 = (float*)LDS;
        red1[tid] = d; __syncthreads();
        for (int o = 128; o > 0; o >>= 1) {
            if (tid < o) red1[tid] += red1[tid + o];
            __syncthreads();
        }
        if (tid == 0) atomicAdd(sumd, red1[0]);
        return;
    }
    {                                               // finalFb pad
        int j = i - P3; int rr = j >> 2;
        finalFb[(size_t)rr * FDP + FD + (j & 3)] = 0;
    }
}

// ---------------------------------------------------------------- scores1 + exp (+router finalize)
__global__ __launch_bounds__(256) void scores_e(
    const short* __restrict__ Q, const short* __restrict__ Kk,
    short* __restrict__ E, float* __restrict__ Z,
    const float* __restrict__ r0acc, const float* __restrict__ rp0acc,
    const float* __restrict__ sumd,
    const float* __restrict__ w1w, const float* __restrict__ w1b,
    const float* __restrict__ w2w,
    float* __restrict__ router0, float* __restrict__ w2r,
    float* __restrict__ w2b1)
{
    __shared__ __align__(16) short LDS[10240];      // 20.5 KB
    const int j = blockIdx.x, tid = threadIdx.x;
    if (j == 512) {                                 // router finalize chain
        float* rp0l = (float*)LDS;                  // 264 floats
        float* r1l = rp0l + 264;                    // 264 floats
        float sd = sumd[0];
        for (int c = tid; c < PD2; c += 256) {
            float r0v = r0acc[c] * (1.0f / (float)N1);
            router0[c] = r0v;
            rp0l[c] = (rp0acc[c] + r0v) / (1.f + sd + 1e-12f);
        }
        __syncthreads();
        for (int c = tid; c < PD2; c += 256) {
            float s = w1b[c];
            const float* wr = w1w + (size_t)c * PD2;
            for (int k = 0; k < PD2; ++k) s += wr[k] * rp0l[k];
            r1l[c] = s;
        }
        __syncthreads();
        for (int c = tid; c < PD2; c += 256) {
            const float* wr = w2w + (size_t)c * PD2;
            float sr = 0.f, sb = 0.f;
            for (int k = 0; k < PD2; ++k) {
                float w = wr[k];
                sr += w * r1l[k];
                sb += w * w1b[k];
            }
            w2r[c] = sr;
            w2b1[c] = sb;
        }
        return;
    }
    short* Als = LDS;
    short* Bls = LDS + 128 * 40;
    const int lane = tid & 63, wv = tid >> 6;
    const int wm = wv >> 1, wn = wv & 1;
    const int lm = lane & 15, lq = lane >> 4;
    const int row0 = (j >> 5) * 128, col0 = (j & 31) * 128;
    const f32x4 zero4 = {0.f, 0.f, 0.f, 0.f};
    f32x4 acc[4][4];
#pragma unroll
    for (int mt = 0; mt < 4; ++mt)
#pragma unroll
        for (int nt = 0; nt < 4; ++nt) acc[mt][nt] = zero4;
    for (int k0 = 0; k0 < 128; k0 += 32) {
#pragma unroll
        for (int l = 0; l < 2; ++l) {
            int id = l * 256 + tid;
            int r = id >> 2, cgp = id & 3;
            int gk = k0 + cgp * 8;
            *(s8v*)(Als + r * 40 + cgp * 8) = *(const s8v*)(Q + (size_t)(row0 + r) * DZ + gk);
            *(s8v*)(Bls + r * 40 + cgp * 8) = *(const s8v*)(Kk + (size_t)(col0 + r) * 256 + gk);
        }
        __syncthreads();
        s8v af[4], bf[4];
#pragma unroll
        for (int mt = 0; mt < 4; ++mt)
            af[mt] = *(const s8v*)(Als + (wm * 64 + mt * 16 + lm) * 40 + lq * 8);
#pragma unroll
        for (int nt = 0; nt < 4; ++nt)
            bf[nt] = *(const s8v*)(Bls + (wn * 64 + nt * 16 + lm) * 40 + lq * 8);
#pragma unroll
        for (int mt = 0; mt < 4; ++mt)
#pragma unroll
            for (int nt = 0; nt < 4; ++nt)
                acc[mt][nt] = __builtin_amdgcn_mfma_f32_16x16x32_bf16(
                    af[mt], bf[nt], acc[mt][nt], 0, 0, 0);
        __syncthreads();
    }
#pragma unroll
    for (int mt = 0; mt < 4; ++mt)
#pragma unroll
        for (int i = 0; i < 4; ++i) {
            int r = row0 + wm * 64 + mt * 16 + lq * 4 + i;
            float rs = 0.f;
#pragma unroll
            for (int nt = 0; nt < 4; ++nt) {
                int c = col0 + wn * 64 + nt * 16 + lm;
                float e = __expf(acc[mt][nt][i]);
                E[(size_t)r * N1 + c] = f2b(e);
                rs += e;
            }
#pragma unroll
            for (int msk = 1; msk < 16; msk <<= 1) rs += __shfl_xor(rs, msk, 64);
            if (lm == 0) atomicAdd(&Z[r], rs);
        }
}

// ---------------------------------------------------------------- AP split-K (512 thr, bf16 partials)
__global__ __launch_bounds__(512) void ap_gemm(const short* __restrict__ E,
                                               const float* __restrict__ Z,
                                               const short* __restrict__ lmFTb,
                                               short* __restrict__ part)
{
    __shared__ __align__(16) short LDS[28800];
    const int tid = threadIdx.x, bid = blockIdx.x;
    const int lane = tid & 63, w8 = tid >> 6;
    const int lm = lane & 15, lq = lane >> 4;
    const int s = bid & 15, row0 = (bid >> 4) * 128;
    const int kbase = s * (N1 / SPLITS);
    short* Als = LDS;
    short* Bls = LDS + 128 * APLD;
    const f32x4 zero4 = {0.f, 0.f, 0.f, 0.f};
    f32x4 acc[17];
#pragma unroll
    for (int nt = 0; nt < 17; ++nt) acc[nt] = zero4;
    for (int it = 0; it < (N1 / SPLITS) / 64; ++it) {
        int k0 = kbase + it * 64;
#pragma unroll
        for (int l = 0; l < 2; ++l) {
            int id = l * 512 + tid;
            int r = id >> 3, gg = id & 7;
            s8v ev = *(const s8v*)(E + (size_t)(row0 + r) * N1 + k0 + gg * 8);
            float invZ = __builtin_amdgcn_rcpf(Z[row0 + r]);
            s8v av;
#pragma unroll
            for (int q = 0; q < 8; ++q)
                av[q] = f2b(__expf(sb2f(ev[q]) * invZ));
            *(s8v*)(Als + r * APLD + gg * 8) = av;
        }
#pragma unroll
        for (int l = 0; l < 5; ++l) {
            int id = l * 512 + tid;
            if (id < APN * 8) {
                int r = id >> 3, gg = id & 7;
                *(s8v*)(Bls + r * APLD + gg * 8) =
                    *(const s8v*)(lmFTb + (size_t)r * N1 + k0 + gg * 8);
            }
        }
        __syncthreads();
        s8v a0 = *(const s8v*)(Als + (w8 * 16 + lm) * APLD + lq * 8);
        s8v a1 = *(const s8v*)(Als + (w8 * 16 + lm) * APLD + 32 + lq * 8);
#pragma unroll
        for (int nt = 0; nt < 17; ++nt) {
            s8v b0 = *(const s8v*)(Bls + (nt * 16 + lm) * APLD + lq * 8);
            s8v b1 = *(const s8v*)(Bls + (nt * 16 + lm) * APLD + 32 + lq * 8);
            acc[nt] = __builtin_amdgcn_mfma_f32_16x16x32_bf16(a0, b0, acc[nt], 0, 0, 0);
            acc[nt] = __builtin_amdgcn_mfma_f32_16x16x32_bf16(a1, b1, acc[nt], 0, 0, 0);
        }
        __syncthreads();
    }
    short* op = part + (size_t)s * N2 * APN;
#pragma unroll
    for (int nt = 0; nt < 17; ++nt) {
        int c = nt * 16 + lm;
#pragma unroll
        for (int i = 0; i < 4; ++i) {
            int r = row0 + w8 * 16 + lq * 4 + i;
            op[(size_t)r * APN + c] = f2b(acc[nt][i]);
        }
    }
}

// ---------------------------------------------------------------- tgp0 reduce+fixup
__global__ __launch_bounds__(256) void fix_tgp0(const short* __restrict__ part,
                                                const float* __restrict__ tgX,
                                                const float* __restrict__ rou0,
                                                const float* __restrict__ router0,
                                                short* __restrict__ outb) {
    int r = blockIdx.x;
    int tid = threadIdx.x;
    __shared__ float sAsum;
    float s0 = 0.f, s1 = 0.f;
#pragma unroll
    for (int s = 0; s < SPLITS; ++s)
        s0 += sb2f(part[((size_t)s * N2 + r) * APN + tid]);
    if (tid < 8) {
#pragma unroll
        for (int s = 0; s < SPLITS; ++s)
            s1 += sb2f(part[((size_t)s * N2 + r) * APN + 256 + tid]);
    }
    if (tid == 2) sAsum = s1;   // col 258
    __syncthreads();
    float ro = rou0[r];
    float inv = 1.f / (1.f + sAsum + ro + 1e-12f);
    {
        float v = (s0 + tgX[(size_t)r * PD + tid] + ro * router0[tid]) * inv;
        outb[(size_t)r * PD2P + tid] = f2b(v);
    }
    if (tid < 8) {
        int c = 256 + tid;
        float v = 0.f;
        if (c < PD2) v = (s1 + ro * router0[c]) * inv;
        outb[(size_t)r * PD2P + c] = f2b(v);
    }
}

// ---------------------------------------------------------------- combined W GEMM
// A = tgp0b [2048][264]; B rows 0..257 = W1 (inline f32->bf16),
// rows 258..515 = M = W2*W1 (bf16), rows 516.. = 0.
// cols j<258 -> tf1; 258<=j<516 -> tf2 via affine.
__global__ __launch_bounds__(256) void wt_gemm(
    const short* __restrict__ A, const float* __restrict__ w1w,
    const short* __restrict__ Mb,
    const float* __restrict__ w1b, const float* __restrict__ w2b,
    const float* __restrict__ rou1, const float* __restrict__ w2r,
    const float* __restrict__ w2b1,
    float* __restrict__ outF, short* __restrict__ finalFb)
{
    __shared__ __align__(16) short LDS[5120];
    short* Als = LDS;
    short* Bls = LDS + 64 * 40;
    const int tid = threadIdx.x;
    const int lane = tid & 63, wv = tid >> 6;
    const int wm = wv >> 1, wn = wv & 1;
    const int lm = lane & 15, lq = lane >> 4;
    const int row0 = blockIdx.y * 64, col0 = blockIdx.x * 64;
    const f32x4 zero4 = {0.f, 0.f, 0.f, 0.f};
    f32x4 acc[2][2] = {{zero4, zero4}, {zero4, zero4}};
    const s8v zero8 = {0, 0, 0, 0, 0, 0, 0, 0};
    const int r = tid >> 2, cgp = tid & 3;
    const int j = col0 + r;
    for (int k0 = 0; k0 < PD2P; k0 += 32) {
        int gk = k0 + cgp * 8;
        s8v va = zero8, vb = zero8;
        if (gk < PD2P)
            va = *(const s8v*)(A + (size_t)(row0 + r) * PD2P + gk);
        if (j < PD2) {
#pragma unroll
            for (int q = 0; q < 8; ++q) {
                int kidx = gk + q;
                if (kidx < PD2) vb[q] = f2b(w1w[(size_t)j * PD2 + kidx]);
            }
        } else if (j < 2 * PD2) {
            if (gk < PD2P) vb = *(const s8v*)(Mb + (size_t)(j - PD2) * PD2P + gk);
        }
        *(s8v*)(Als + r * 40 + cgp * 8) = va;
        *(s8v*)(Bls + r * 40 + cgp * 8) = vb;
        __syncthreads();
        s8v af[2], bf[2];
#pragma unroll
        for (int mt = 0; mt < 2; ++mt)
            af[mt] = *(const s8v*)(Als + (wm * 32 + mt * 16 + lm) * 40 + lq * 8);
#pragma unroll
        for (int nt = 0; nt < 2; ++nt)
            bf[nt] = *(const s8v*)(Bls + (wn * 32 + nt * 16 + lm) * 40 + lq * 8);
#pragma unroll
        for (int mt = 0; mt < 2; ++mt)
#pragma unroll
            for (int nt = 0; nt < 2; ++nt)
                acc[mt][nt] = __builtin_amdgcn_mfma_f32_16x16x32_bf16(
                    af[mt], bf[nt], acc[mt][nt], 0, 0, 0);
        __syncthreads();
    }
#pragma unroll
    for (int mt = 0; mt < 2; ++mt)
#pragma unroll
        for (int nt = 0; nt < 2; ++nt) {
            int jc = col0 + wn * 32 + nt * 16 + lm;
            if (jc >= 2 * PD2) continue;
#pragma unroll
            for (int i = 0; i < 4; ++i) {
                int rr = row0 + wm * 32 + mt * 16 + lq * 4 + i;
                float v;
                int oc;
                if (jc < PD2) {
                    v = acc[mt][nt][i] + w1b[jc];
                    oc = 256 + jc;
                } else {
                    int c = jc - PD2;
                    float ro = rou1[rr];
                    v = (acc[mt][nt][i] + w2b1[c] + ro * w2r[c]) / (1.f + ro + 1e-12f)
                        + w2b[c];
                    oc = 514 + c;
                }
                outF[(size_t)rr * FD + oc] = v;
                finalFb[(size_t)rr * FDP + oc] = f2b(v);
            }
        }
}

// ---------------------------------------------------------------- q2 projection (K=776)
__global__ __launch_bounds__(256) void q2_gemm(
    const short* __restrict__ A, const short* __restrict__ B,
    const float* __restrict__ bias, short* __restrict__ outB)
{
    __shared__ __align__(16) short LDS[5120];
    short* Als = LDS;
    short* Bls = LDS + 64 * 40;
    const int tid = threadIdx.x;
    const int lane = tid & 63, wv = tid >> 6;
    const int wm = wv >> 1, wn = wv & 1;
    const int lm = lane & 15, lq = lane >> 4;
    const int row0 = blockIdx.y * 64, col0 = blockIdx.x * 64;
    const f32x4 zero4 = {0.f, 0.f, 0.f, 0.f};
    f32x4 acc[2][2] = {{zero4, zero4}, {zero4, zero4}};
    const s8v zero8 = {0, 0, 0, 0, 0, 0, 0, 0};
    const int r = tid >> 2, cgp = tid & 3;
    for (int k0 = 0; k0 < FDP; k0 += 32) {
        int gk = k0 + cgp * 8;
        s8v va = zero8, vb = zero8;
        if (gk < FDP) {
            va = *(const s8v*)(A + (size_t)(row0 + r) * FDP + gk);
            vb = *(const s8v*)(B + (size_t)(col0 + r) * FDP + gk);
        }
        *(s8v*)(Als + r * 40 + cgp * 8) = va;
        *(s8v*)(Bls + r * 40 + cgp * 8) = vb;
        __syncthreads();
        s8v af[2], bf[2];
#pragma unroll
        for (int mt = 0; mt < 2; ++mt)
            af[mt] = *(const s8v*)(Als + (wm * 32 + mt * 16 + lm) * 40 + lq * 8);
#pragma unroll
        for (int nt = 0; nt < 2; ++nt)
            bf[nt] = *(const s8v*)(Bls + (wn * 32 + nt * 16 + lm) * 40 + lq * 8);
#pragma unroll
        for (int mt = 0; mt < 2; ++mt)
#pragma unroll
            for (int nt = 0; nt < 2; ++nt)
                acc[mt][nt] = __builtin_amdgcn_mfma_f32_16x16x32_bf16(
                    af[mt], bf[nt], acc[mt][nt], 0, 0, 0);
        __syncthreads();
    }
    const float INV_TEMP = 0.08838834764831845f;
#pragma unroll
    for (int mt = 0; mt < 2; ++mt)
#pragma unroll
        for (int nt = 0; nt < 2; ++nt) {
            int c = col0 + wn * 32 + nt * 16 + lm;
            float bv = bias[c];
#pragma unroll
            for (int i = 0; i < 4; ++i) {
                int rr = row0 + wm * 32 + mt * 16 + lq * 4 + i;
                outB[(size_t)rr * DZ + c] = f2b(INV_TEMP * (acc[mt][nt][i] + bv));
            }
        }
}

// ---------------------------------------------------------------- attention 2
__global__ __launch_bounds__(256) void attn2_flash(
    const short* __restrict__ Q, const short* __restrict__ Kk,
    const float* __restrict__ V, float* __restrict__ part2)
{
    __shared__ __align__(16) short Qls[64 * 136];
    __shared__ __align__(16) short Kls[64 * 136];
    __shared__ float Vls[128];
    const int tid = threadIdx.x;
    const int lane = tid & 63, wv = tid >> 6;
    const int lm = lane & 15, lq = lane >> 4;
    const int chunk = blockIdx.x & 15, row0 = (blockIdx.x >> 4) * 64;
    const f32x4 zero4 = {0.f, 0.f, 0.f, 0.f};
#pragma unroll
    for (int l = 0; l < 4; ++l) {
        int id = l * 256 + tid;
        int r = id >> 4, g = id & 15;
        *(s8v*)(Qls + r * 136 + g * 8) = *(const s8v*)(Q + (size_t)(row0 + r) * DZ + g * 8);
    }
    __syncthreads();
    s8v af[4];
#pragma unroll
    for (int ks = 0; ks < 4; ++ks)
        af[ks] = *(const s8v*)(Qls + (wv * 16 + lm) * 136 + ks * 32 + lq * 8);
    float z[4] = {0.f, 0.f, 0.f, 0.f};
    float y0[4] = {0.f, 0.f, 0.f, 0.f};
    float y1[4] = {0.f, 0.f, 0.f, 0.f};
    for (int t = 0; t < 4; ++t) {
        int col0 = chunk * 256 + t * 64;
        __syncthreads();
#pragma unroll
        for (int l = 0; l < 4; ++l) {
            int id = l * 256 + tid;
            int r = id >> 4, g = id & 15;
            *(s8v*)(Kls + r * 136 + g * 8) =
                *(const s8v*)(Kk + (size_t)(col0 + r) * 256 + 128 + g * 8);
        }
        if (tid < 128) Vls[tid] = V[col0 * 2 + tid];
        __syncthreads();
        f32x4 acc[4];
#pragma unroll
        for (int nt = 0; nt < 4; ++nt) acc[nt] = zero4;
#pragma unroll
        for (int nt = 0; nt < 4; ++nt)
#pragma unroll
            for (int ks = 0; ks < 4; ++ks) {
                s8v bf = *(const s8v*)(Kls + (nt * 16 + lm) * 136 + ks * 32 + lq * 8);
                acc[nt] = __builtin_amdgcn_mfma_f32_16x16x32_bf16(af[ks], bf, acc[nt], 0, 0, 0);
            }
        float v0[4], v1[4];
#pragma unroll
        for (int nt = 0; nt < 4; ++nt) {
            v0[nt] = Vls[(nt * 16 + lm) * 2];
            v1[nt] = Vls[(nt * 16 + lm) * 2 + 1];
        }
#pragma unroll
        for (int i = 0; i < 4; ++i) {
            float e0 = __expf(acc[0][i]), e1 = __expf(acc[1][i]);
            float e2 = __expf(acc[2][i]), e3 = __expf(acc[3][i]);
            z[i]  += e0 + e1 + e2 + e3;
            y0[i] += e0 * v0[0] + e1 * v0[1] + e2 * v0[2] + e3 * v0[3];
            y1[i] += e0 * v1[0] + e1 * v1[1] + e2 * v1[2] + e3 * v1[3];
        }
    }
#pragma unroll
    for (int i = 0; i < 4; ++i) {
#pragma unroll
        for (int msk = 1; msk < 16; msk <<= 1) {
            z[i]  += __shfl_xor(z[i], msk, 64);
            y0[i] += __shfl_xor(y0[i], msk, 64);
            y1[i] += __shfl_xor(y1[i], msk, 64);
        }
    }
    if (lm == 0) {
#pragma unroll
        for (int i = 0; i < 4; ++i) {
            int r = row0 + wv * 16 + lq * 4 + i;
            float* pp = part2 + ((size_t)r * 16 + chunk) * 4;
            pp[0] = z[i]; pp[1] = y0[i]; pp[2] = y1[i];
        }
    }
}

__global__ void attn2_combine(const float* __restrict__ part2, float* __restrict__ out) {
    int r = blockIdx.x * 256 + threadIdx.x;
    if (r >= N2) return;
    const float* pp = part2 + (size_t)r * 64;
    float Zt = 0.f, Y0 = 0.f, Y1 = 0.f;
#pragma unroll
    for (int c = 0; c < 16; ++c) {
        Zt += pp[c * 4]; Y0 += pp[c * 4 + 1]; Y1 += pp[c * 4 + 2];
    }
    out[2 * r] = Y0 / Zt;
    out[2 * r + 1] = Y1 / Zt;
}

// ---------------------------------------------------------------- launch
extern "C" void kernel_launch(void* const* d_in, const int* in_sizes, int n_in,
                              void* d_out, int out_size, void* d_ws, size_t ws_size,
                              hipStream_t stream) {
    const float* lm_X = (const float*)d_in[0];
    const float* lm_Y = (const float*)d_in[1];
    const float* tg_X = (const float*)d_in[2];
    const float* lm_delay = (const float*)d_in[4];
    const float* tg_delay = (const float*)d_in[5];
    const float* aq_w = (const float*)d_in[6];
    const float* aq_b = (const float*)d_in[7];
    const float* ak_w = (const float*)d_in[8];
    const float* ak_b = (const float*)d_in[9];
    const float* w1_w = (const float*)d_in[10];
    const float* w1_b = (const float*)d_in[11];
    const float* w2_w = (const float*)d_in[12];
    const float* w2_b = (const float*)d_in[13];
    const float* pq_w = (const float*)d_in[14];
    const float* pq_b = (const float*)d_in[15];
    const float* pk_w = (const float*)d_in[16];
    const float* pk_b = (const float*)d_in[17];
    const float* pv_w = (const float*)d_in[18];
    const float* pv_b = (const float*)d_in[19];
    const float* g1 = (const float*)d_in[20];
    const float* g2 = (const float*)d_in[21];
    const float* g3 = (const float*)d_in[22];
    const float* al = (const float*)d_in[23];
    const float* be = (const float*)d_in[24];

    float* out = (float*)d_out;
    float* outF = out + (size_t)N2 * 2;

    char* base = (char*)d_ws;
    size_t off = 0;
    auto allocF = [&](size_t n) -> float* {
        float* q = (float*)(base + off);
        off += (n * 4 + 255) / 256 * 256;
        return q;
    };
    auto allocS = [&](size_t n) -> short* {
        short* q = (short*)(base + off);
        off += (n * 2 + 255) / 256 * 256;
        return q;
    };

    short* E        = allocS((size_t)N2 * N1);
    short* appart   = allocS((size_t)SPLITS * N2 * APN);
    short* lmFTb    = allocS((size_t)APN * N1);
    short* qb       = allocS((size_t)N2 * DZ);
    short* kk       = allocS((size_t)N1 * 256);
    short* q2       = allocS((size_t)N2 * DZ);
    short* tgp0b    = allocS((size_t)N2 * PD2P);
    short* finalFb  = allocS((size_t)N2 * FDP);
    short* pqwb     = allocS((size_t)DZ * FDP);
    short* Mb       = allocS((size_t)PD2 * PD2P);
    float* v2b      = allocF((size_t)N1 * 2);
    float* part2    = allocF((size_t)N2 * 64);
    // zero-init block: Z[2048] | r0acc[264] | rp0acc[264] | sumd[8]
    float* Zr       = allocF(2048 + 264 + 264 + 8);
    float* Zbuf     = Zr;
    float* r0acc    = Zr + 2048;
    float* rp0acc   = Zr + 2048 + 264;
    float* sumd     = Zr + 2048 + 528;
    float* router0  = allocF(264);
    float* w2r      = allocF(264);
    float* w2b1     = allocF(264);
    float* rou0     = allocF(N2);
    float* rou1     = allocF(N2);

    hipMemsetAsync(Zr, 0, (2048 + 264 + 264 + 8) * sizeof(float), stream);

    // 1. prep: conversions, transpose + router atomics, kk/qb/M GEMMs
    hipLaunchKernelGGL(prep, dim3(GB_FL + P4 / 256), dim3(256), 0, stream,
                       lm_X, lm_Y, tg_X, aq_w, aq_b, ak_w, ak_b, pk_w, pk_b,
                       pq_w, w1_w, w2_w, lm_delay, tg_delay,
                       g1, g2, g3, al, be, pv_w, pv_b,
                       outF, finalFb, pqwb, lmFTb, rou0, rou1, v2b,
                       r0acc, rp0acc, sumd, kk, qb, Mb);
    // 2. E = exp(scores), Z rowsums; block 512 finalizes router chain
    hipLaunchKernelGGL(scores_e, dim3(513), dim3(256), 0, stream,
                       qb, kk, E, Zbuf, r0acc, rp0acc, sumd,
                       w1_w, w1_b, w2_w, router0, w2r, w2b1);
    // 3. AP partials
    hipLaunchKernelGGL(ap_gemm, dim3(256), dim3(512), 0, stream, E, Zbuf, lmFTb, appart);
    // 4. tgp0
    hipLaunchKernelGGL(fix_tgp0, dim3(N2), dim3(256), 0, stream,
                       appart, tg_X, rou0, router0, tgp0b);
    // 5. combined W-layer: tf1 + tf2 in one GEMM
    hipLaunchKernelGGL(wt_gemm, dim3(9, 32), dim3(256), 0, stream,
                       tgp0b, w1_w, Mb, w1_b, w2_b, rou1, w2r, w2b1,
                       outF, finalFb);
    // 6. q2
    hipLaunchKernelGGL(q2_gemm, dim3(2, 32), dim3(256), 0, stream,
                       finalFb, pqwb, pq_b, q2);
    // 7-8. attention 2 + combine
    hipLaunchKernelGGL(attn2_flash, dim3(512), dim3(256), 0, stream,
                       q2, kk, v2b, part2);
    hipLaunchKernelGGL(attn2_combine, dim3(8), dim3(256), 0, stream, part2, out);
}

// Round 12
// 220.447 us; speedup vs baseline: 1.2084x; 1.2084x over previous
//
#include <hip/hip_runtime.h>

#define N1 4096
#define N2 2048
#define PD 256
#define DZ 128
#define PD2 258
#define PD2P 264
#define FD 772
#define FDP 776
#define APN 272      // lmFT rows padded; row 258 = ones -> attr_sum
#define APLD 72
#define SPLITS 16

typedef short s8v __attribute__((ext_vector_type(8)));
typedef float f32x4 __attribute__((ext_vector_type(4)));

__device__ __forceinline__ short f2b(float f) {
    union { float f; unsigned u; } v; v.f = f;
    unsigned r = v.u + 0x7fffu + ((v.u >> 16) & 1u);
    return (short)(r >> 16);
}
__device__ __forceinline__ float sb2f(short s) {
    union { unsigned u; float f; } v;
    v.u = ((unsigned)(unsigned short)s) << 16;
    return v.f;
}

// ---------------------------------------------------------------- cvt_all
// blocks [0, GT): LDS-tiled lmFT transpose (coalesced both ways)
// blocks [GT, ...): flat regions
#define GT 320
constexpr int Q0 = N2 * PD;            // tgX -> outF / finalFb cols 0..255
constexpr int Q1 = Q0 + PD2 * PD2P;    // w1wb
constexpr int Q2 = Q1 + PD2 * PD2P;    // w2wb
constexpr int Q3 = Q2 + DZ * FDP;      // pqwb
constexpr int Q4 = Q3 + 4096;          // delay / v2 / dscore
constexpr int Q5 = Q4 + 2048;          // Z zero
constexpr int Q6 = Q5 + N2 * 4;        // finalFb pad
constexpr int Q7 = Q6 + N2 * 6;        // tgp1b pad
#define FLAT_BLOCKS ((Q7 + 255) / 256)

__global__ __launch_bounds__(256) void cvt_all(
    const float* __restrict__ lmX, const float* __restrict__ lmY,
    const float* __restrict__ tgX,
    const float* __restrict__ pqw, const float* __restrict__ w1w,
    const float* __restrict__ w2w,
    const float* __restrict__ lmd, const float* __restrict__ tgd,
    const float* __restrict__ g1, const float* __restrict__ g2,
    const float* __restrict__ g3, const float* __restrict__ al,
    const float* __restrict__ be,
    const float* __restrict__ pvw, const float* __restrict__ pvb,
    short* __restrict__ w1wb, short* __restrict__ w2wb,
    short* __restrict__ pqwb, short* __restrict__ lmFTb,
    float* __restrict__ dscore, float* __restrict__ rou0,
    float* __restrict__ rou1, float* __restrict__ v2b,
    float* __restrict__ Z, short* __restrict__ finalFb,
    short* __restrict__ tgp1b, float* __restrict__ outF)
{
    __shared__ __align__(16) short TLS[64 * 65];   // 8.3 KB
    const int bid = blockIdx.x, tid = threadIdx.x;
    if (bid < GT) {                                 // tiled transpose
        int rt = bid / 5, ct = bid - rt * 5;
        int r0 = rt * 64, c0 = ct * 64;
#pragma unroll
        for (int l = 0; l < 16; ++l) {
            int idx = l * 256 + tid;
            int i = idx >> 6, jj = idx & 63;
            int c = c0 + jj;
            float v = 0.f;
            if (c < PD) v = lmX[(size_t)(r0 + i) * PD + c];
            else if (c < PD2) v = lmY[(size_t)(r0 + i) * 2 + (c - PD)];
            else if (c == PD2) v = 1.f;             // ones col -> attr_sum
            TLS[jj * 65 + i] = f2b(v);
        }
        __syncthreads();
#pragma unroll
        for (int l = 0; l < 16; ++l) {
            int idx = l * 256 + tid;
            int cc = idx >> 6, i = idx & 63;
            if (c0 + cc < APN)
                lmFTb[(size_t)(c0 + cc) * N1 + r0 + i] = TLS[cc * 65 + i];
        }
        return;
    }
    int i = (bid - GT) * 256 + tid;
    if (i < Q0) { int r = i >> 8, c = i & 255;
                  float v = tgX[i];
                  outF[(size_t)r * FD + c] = v;
                  finalFb[(size_t)r * FDP + c] = f2b(v); return; }
    if (i < Q1) { int j = i - Q0; int r = j / PD2P, c = j - r * PD2P;
                  w1wb[j] = (c < PD2) ? f2b(w1w[r * PD2 + c]) : (short)0; return; }
    if (i < Q2) { int j = i - Q1; int r = j / PD2P, c = j - r * PD2P;
                  w2wb[j] = (c < PD2) ? f2b(w2w[r * PD2 + c]) : (short)0; return; }
    if (i < Q3) { int j = i - Q2; int r = j / FDP, c = j - r * FDP;
                  pqwb[j] = (c < FD) ? f2b(pqw[r * FD + c]) : (short)0; return; }
    if (i < Q4) { int j = i - Q3;   // j in [0,4096)
                  float a = al[0], b = be[0];
                  dscore[j] = __expf(-g1[0] * (a * lmd[j] + b));
                  float y0 = lmY[2 * j], y1 = lmY[2 * j + 1];
                  v2b[2 * j]     = pvw[0] * y0 + pvw[1] * y1 + pvb[0];
                  v2b[2 * j + 1] = pvw[2] * y0 + pvw[3] * y1 + pvb[1];
                  if (j < N2) { float t = a * tgd[j] + b;
                                rou0[j] = __expf(-g2[0] * t);
                                rou1[j] = __expf(-g3[0] * t); }
                  return; }
    if (i < Q5) { Z[i - Q4] = 0.f; return; }
    if (i < Q6) { int j = i - Q5; int r = j >> 2;
                  finalFb[(size_t)r * FDP + FD + (j & 3)] = 0; return; }
    if (i < Q7) { int j = i - Q6; int r = j / 6;
                  tgp1b[(size_t)r * PD2P + PD2 + (j - r * 6)] = 0; return; }
}

// ---------------------------------------------------------------- router + kk + qb
__global__ __launch_bounds__(256) void rkq_kernel(
    const float* __restrict__ lmX, const float* __restrict__ tgX,
    const float* __restrict__ aqw, const float* __restrict__ aqb,
    const float* __restrict__ akw, const float* __restrict__ akb,
    const float* __restrict__ pkw, const float* __restrict__ pkb,
    const short* __restrict__ lmFTb, const float* __restrict__ dscore,
    float* __restrict__ router0, float* __restrict__ routerp0,
    short* __restrict__ kk, short* __restrict__ qb)
{
    __shared__ __align__(16) short LDS[5120];      // 10.2 KB
    const int j = blockIdx.x, tid = threadIdx.x;
    const int lane = tid & 63, wv = tid >> 6;
    const int wm = wv >> 1, wn = wv & 1;
    const int lm = lane & 15, lq = lane >> 4;
    const f32x4 zero4 = {0.f, 0.f, 0.f, 0.f};

    if (j < 258) {                                 // router column
        float* r1 = (float*)LDS;
        float* r2 = r1 + 256;
        float* r3 = r2 + 256;
        const short* rowp = lmFTb + (size_t)j * N1;
        float s1 = 0.f, s2 = 0.f, s3 = 0.f;
        for (int i = tid; i < N1; i += 256) {
            float v = sb2f(rowp[i]);
            float d = dscore[i];
            s1 += v; s2 += d * v; s3 += d;
        }
        r1[tid] = s1; r2[tid] = s2; r3[tid] = s3; __syncthreads();
        for (int o = 128; o > 0; o >>= 1) {
            if (tid < o) { r1[tid] += r1[tid + o]; r2[tid] += r2[tid + o]; r3[tid] += r3[tid + o]; }
            __syncthreads();
        }
        if (tid == 0) {
            float r0v = r1[0] / (float)N1;
            router0[j] = r0v;
            routerp0[j] = (r2[0] + r0v) / (1.f + r3[0] + 1e-12f);
        }
        return;
    }
    short* Als = LDS;
    short* Bls = LDS + 64 * 40;
    f32x4 acc[2][2] = {{zero4, zero4}, {zero4, zero4}};
    const int r = tid >> 2, cgp = tid & 3;
    if (j < 514) {                                 // kk tile
        int jt = j - 258;
        int row0 = (jt >> 2) * 64, col0 = (jt & 3) * 64;
        for (int k0 = 0; k0 < 256; k0 += 32) {
            int gk = k0 + cgp * 8;
            const float* ap = lmX + (size_t)(row0 + r) * PD + gk;
            int c = col0 + r;
            const float* bp = (c < 128) ? akw + (size_t)c * PD + gk
                                        : pkw + (size_t)(c - 128) * PD + gk;
            s8v va, vb;
#pragma unroll
            for (int q = 0; q < 8; ++q) { va[q] = f2b(ap[q]); vb[q] = f2b(bp[q]); }
            *(s8v*)(Als + r * 40 + cgp * 8) = va;
            *(s8v*)(Bls + r * 40 + cgp * 8) = vb;
            __syncthreads();
            s8v af[2], bf[2];
#pragma unroll
            for (int mt = 0; mt < 2; ++mt)
                af[mt] = *(const s8v*)(Als + (wm * 32 + mt * 16 + lm) * 40 + lq * 8);
#pragma unroll
            for (int nt = 0; nt < 2; ++nt)
                bf[nt] = *(const s8v*)(Bls + (wn * 32 + nt * 16 + lm) * 40 + lq * 8);
#pragma unroll
            for (int mt = 0; mt < 2; ++mt)
#pragma unroll
                for (int nt = 0; nt < 2; ++nt)
                    acc[mt][nt] = __builtin_amdgcn_mfma_f32_16x16x32_bf16(
                        af[mt], bf[nt], acc[mt][nt], 0, 0, 0);
            __syncthreads();
        }
#pragma unroll
        for (int mt = 0; mt < 2; ++mt)
#pragma unroll
            for (int nt = 0; nt < 2; ++nt) {
                int c = col0 + wn * 32 + nt * 16 + lm;
                float bv = (c < 128) ? akb[c] : pkb[c - 128];
#pragma unroll
                for (int i = 0; i < 4; ++i) {
                    int rr = row0 + wm * 32 + mt * 16 + lq * 4 + i;
                    kk[(size_t)rr * 256 + c] = f2b(acc[mt][nt][i] + bv);
                }
            }
    } else {                                       // qb tile
        int jt = j - 514;
        int row0 = (jt >> 1) * 64, col0 = (jt & 1) * 64;
        for (int k0 = 0; k0 < 256; k0 += 32) {
            int gk = k0 + cgp * 8;
            const float* ap = tgX + (size_t)(row0 + r) * PD + gk;
            const float* bp = aqw + (size_t)(col0 + r) * PD + gk;
            s8v va, vb;
#pragma unroll
            for (int q = 0; q < 8; ++q) { va[q] = f2b(ap[q]); vb[q] = f2b(bp[q]); }
            *(s8v*)(Als + r * 40 + cgp * 8) = va;
            *(s8v*)(Bls + r * 40 + cgp * 8) = vb;
            __syncthreads();
            s8v af[2], bf[2];
#pragma unroll
            for (int mt = 0; mt < 2; ++mt)
                af[mt] = *(const s8v*)(Als + (wm * 32 + mt * 16 + lm) * 40 + lq * 8);
#pragma unroll
            for (int nt = 0; nt < 2; ++nt)
                bf[nt] = *(const s8v*)(Bls + (wn * 32 + nt * 16 + lm) * 40 + lq * 8);
#pragma unroll
            for (int mt = 0; mt < 2; ++mt)
#pragma unroll
                for (int nt = 0; nt < 2; ++nt)
                    acc[mt][nt] = __builtin_amdgcn_mfma_f32_16x16x32_bf16(
                        af[mt], bf[nt], acc[mt][nt], 0, 0, 0);
            __syncthreads();
        }
        const float INV_TEMP = 0.08838834764831845f;
#pragma unroll
        for (int mt = 0; mt < 2; ++mt)
#pragma unroll
            for (int nt = 0; nt < 2; ++nt) {
                int c = col0 + wn * 32 + nt * 16 + lm;
                float bv = aqb[c];
#pragma unroll
                for (int i = 0; i < 4; ++i) {
                    int rr = row0 + wm * 32 + mt * 16 + lq * 4 + i;
                    qb[(size_t)rr * DZ + c] = f2b(INV_TEMP * (acc[mt][nt][i] + bv));
                }
            }
    }
}

// ---------------------------------------------------------------- scores1 + exp (+router1)
__global__ __launch_bounds__(256) void scores_e(
    const short* __restrict__ Q, const short* __restrict__ Kk,
    short* __restrict__ E, float* __restrict__ Z,
    const float* __restrict__ rp0, const float* __restrict__ w1w,
    const float* __restrict__ w1b, float* __restrict__ router1)
{
    const int j = blockIdx.x, tid = threadIdx.x;
    if (j == 512) {                                // router1
        for (int c = tid; c < PD2; c += 256) {
            float s = w1b[c];
            const float* wr = w1w + (size_t)c * PD2;
            for (int k = 0; k < PD2; ++k) s += rp0[k] * wr[k];
            router1[c] = s;
        }
        return;
    }
    __shared__ __align__(16) short LDS[10240];     // 2 x 128 x 40
    short* Als = LDS;
    short* Bls = LDS + 128 * 40;
    const int lane = tid & 63, wv = tid >> 6;
    const int wm = wv >> 1, wn = wv & 1;
    const int lm = lane & 15, lq = lane >> 4;
    const int row0 = (j >> 5) * 128, col0 = (j & 31) * 128;
    const f32x4 zero4 = {0.f, 0.f, 0.f, 0.f};
    f32x4 acc[4][4];
#pragma unroll
    for (int mt = 0; mt < 4; ++mt)
#pragma unroll
        for (int nt = 0; nt < 4; ++nt) acc[mt][nt] = zero4;
    for (int k0 = 0; k0 < 128; k0 += 32) {
#pragma unroll
        for (int l = 0; l < 2; ++l) {
            int id = l * 256 + tid;
            int r = id >> 2, cgp = id & 3;
            int gk = k0 + cgp * 8;
            *(s8v*)(Als + r * 40 + cgp * 8) = *(const s8v*)(Q + (size_t)(row0 + r) * DZ + gk);
            *(s8v*)(Bls + r * 40 + cgp * 8) = *(const s8v*)(Kk + (size_t)(col0 + r) * 256 + gk);
        }
        __syncthreads();
        s8v af[4], bf[4];
#pragma unroll
        for (int mt = 0; mt < 4; ++mt)
            af[mt] = *(const s8v*)(Als + (wm * 64 + mt * 16 + lm) * 40 + lq * 8);
#pragma unroll
        for (int nt = 0; nt < 4; ++nt)
            bf[nt] = *(const s8v*)(Bls + (wn * 64 + nt * 16 + lm) * 40 + lq * 8);
#pragma unroll
        for (int mt = 0; mt < 4; ++mt)
#pragma unroll
            for (int nt = 0; nt < 4; ++nt)
                acc[mt][nt] = __builtin_amdgcn_mfma_f32_16x16x32_bf16(
                    af[mt], bf[nt], acc[mt][nt], 0, 0, 0);
        __syncthreads();
    }
#pragma unroll
    for (int mt = 0; mt < 4; ++mt)
#pragma unroll
        for (int i = 0; i < 4; ++i) {
            int r = row0 + wm * 64 + mt * 16 + lq * 4 + i;
            float rs = 0.f;
#pragma unroll
            for (int nt = 0; nt < 4; ++nt) {
                int c = col0 + wn * 64 + nt * 16 + lm;
                float e = __expf(acc[mt][nt][i]);
                E[(size_t)r * N1 + c] = f2b(e);
                rs += e;
            }
#pragma unroll
            for (int msk = 1; msk < 16; msk <<= 1) rs += __shfl_xor(rs, msk, 64);
            if (lm == 0) atomicAdd(&Z[r], rs);
        }
}

// ---------------------------------------------------------------- AP split-K (512 thr, bf16 partials)
__global__ __launch_bounds__(512) void ap_gemm(const short* __restrict__ E,
                                               const float* __restrict__ Z,
                                               const short* __restrict__ lmFTb,
                                               short* __restrict__ part)
{
    __shared__ __align__(16) short LDS[28800];     // 57.6 KB
    const int tid = threadIdx.x, bid = blockIdx.x;
    const int lane = tid & 63, w8 = tid >> 6;
    const int lm = lane & 15, lq = lane >> 4;
    const int s = bid & 15, row0 = (bid >> 4) * 128;
    const int kbase = s * (N1 / SPLITS);
    short* Als = LDS;
    short* Bls = LDS + 128 * APLD;
    const f32x4 zero4 = {0.f, 0.f, 0.f, 0.f};
    f32x4 acc[17];
#pragma unroll
    for (int nt = 0; nt < 17; ++nt) acc[nt] = zero4;
    for (int it = 0; it < (N1 / SPLITS) / 64; ++it) {
        int k0 = kbase + it * 64;
#pragma unroll
        for (int l = 0; l < 2; ++l) {
            int id = l * 512 + tid;
            int r = id >> 3, gg = id & 7;
            s8v ev = *(const s8v*)(E + (size_t)(row0 + r) * N1 + k0 + gg * 8);
            float invZ = __builtin_amdgcn_rcpf(Z[row0 + r]);
            s8v av;
#pragma unroll
            for (int q = 0; q < 8; ++q)
                av[q] = f2b(__expf(sb2f(ev[q]) * invZ));
            *(s8v*)(Als + r * APLD + gg * 8) = av;
        }
#pragma unroll
        for (int l = 0; l < 5; ++l) {
            int id = l * 512 + tid;
            if (id < APN * 8) {
                int r = id >> 3, gg = id & 7;
                *(s8v*)(Bls + r * APLD + gg * 8) =
                    *(const s8v*)(lmFTb + (size_t)r * N1 + k0 + gg * 8);
            }
        }
        __syncthreads();
        s8v a0 = *(const s8v*)(Als + (w8 * 16 + lm) * APLD + lq * 8);
        s8v a1 = *(const s8v*)(Als + (w8 * 16 + lm) * APLD + 32 + lq * 8);
#pragma unroll
        for (int nt = 0; nt < 17; ++nt) {
            s8v b0 = *(const s8v*)(Bls + (nt * 16 + lm) * APLD + lq * 8);
            s8v b1 = *(const s8v*)(Bls + (nt * 16 + lm) * APLD + 32 + lq * 8);
            acc[nt] = __builtin_amdgcn_mfma_f32_16x16x32_bf16(a0, b0, acc[nt], 0, 0, 0);
            acc[nt] = __builtin_amdgcn_mfma_f32_16x16x32_bf16(a1, b1, acc[nt], 0, 0, 0);
        }
        __syncthreads();
    }
    short* op = part + (size_t)s * N2 * APN;
#pragma unroll
    for (int nt = 0; nt < 17; ++nt) {
        int c = nt * 16 + lm;
#pragma unroll
        for (int i = 0; i < 4; ++i) {
            int r = row0 + w8 * 16 + lq * 4 + i;
            op[(size_t)r * APN + c] = f2b(acc[nt][i]);
        }
    }
}

// ---------------------------------------------------------------- tgp0 reduce+fixup
__global__ __launch_bounds__(256) void fix_tgp0(const short* __restrict__ part,
                                                const float* __restrict__ tgX,
                                                const float* __restrict__ rou0,
                                                const float* __restrict__ router0,
                                                short* __restrict__ outb) {
    int r = blockIdx.x;
    int tid = threadIdx.x;
    __shared__ float sAsum;
    float s0 = 0.f, s1 = 0.f;
#pragma unroll
    for (int s = 0; s < SPLITS; ++s)
        s0 += sb2f(part[((size_t)s * N2 + r) * APN + tid]);
    if (tid < 8) {
#pragma unroll
        for (int s = 0; s < SPLITS; ++s)
            s1 += sb2f(part[((size_t)s * N2 + r) * APN + 256 + tid]);
    }
    if (tid == 2) sAsum = s1;   // col 258
    __syncthreads();
    float ro = rou0[r];
    float inv = 1.f / (1.f + sAsum + ro + 1e-12f);
    {
        float v = (s0 + tgX[(size_t)r * PD + tid] + ro * router0[tid]) * inv;
        outb[(size_t)r * PD2P + tid] = f2b(v);
    }
    if (tid < 8) {
        int c = 256 + tid;
        float v = 0.f;
        if (c < PD2) v = (s1 + ro * router0[c]) * inv;
        outb[(size_t)r * PD2P + c] = f2b(v);
    }
}

// ---------------------------------------------------------------- W-layer GEMM
__global__ __launch_bounds__(256) void w_gemm(
    const short* __restrict__ A, const short* __restrict__ B,
    const float* __restrict__ bias,
    float* __restrict__ outFcol, short* __restrict__ fFbcol,
    const float* __restrict__ rou1, const float* __restrict__ router1,
    short* __restrict__ tgp1b)
{
    __shared__ __align__(16) short LDS[5120];
    short* Als = LDS;
    short* Bls = LDS + 64 * 40;
    const int tid = threadIdx.x;
    const int lane = tid & 63, wv = tid >> 6;
    const int wm = wv >> 1, wn = wv & 1;
    const int lm = lane & 15, lq = lane >> 4;
    const int row0 = blockIdx.y * 64, col0 = blockIdx.x * 64;
    const f32x4 zero4 = {0.f, 0.f, 0.f, 0.f};
    f32x4 acc[2][2] = {{zero4, zero4}, {zero4, zero4}};
    const s8v zero8 = {0, 0, 0, 0, 0, 0, 0, 0};
    const int r = tid >> 2, cgp = tid & 3;
    for (int k0 = 0; k0 < PD2P; k0 += 32) {
        int gk = k0 + cgp * 8;
        s8v va = zero8, vb = zero8;
        if (gk < PD2P) {
            va = *(const s8v*)(A + (size_t)(row0 + r) * PD2P + gk);
            if (col0 + r < PD2) vb = *(const s8v*)(B + (size_t)(col0 + r) * PD2P + gk);
        }
        *(s8v*)(Als + r * 40 + cgp * 8) = va;
        *(s8v*)(Bls + r * 40 + cgp * 8) = vb;
        __syncthreads();
        s8v af[2], bf[2];
#pragma unroll
        for (int mt = 0; mt < 2; ++mt)
            af[mt] = *(const s8v*)(Als + (wm * 32 + mt * 16 + lm) * 40 + lq * 8);
#pragma unroll
        for (int nt = 0; nt < 2; ++nt)
            bf[nt] = *(const s8v*)(Bls + (wn * 32 + nt * 16 + lm) * 40 + lq * 8);
#pragma unroll
        for (int mt = 0; mt < 2; ++mt)
#pragma unroll
            for (int nt = 0; nt < 2; ++nt)
                acc[mt][nt] = __builtin_amdgcn_mfma_f32_16x16x32_bf16(
                    af[mt], bf[nt], acc[mt][nt], 0, 0, 0);
        __syncthreads();
    }
#pragma unroll
    for (int mt = 0; mt < 2; ++mt)
#pragma unroll
        for (int nt = 0; nt < 2; ++nt) {
            int c = col0 + wn * 32 + nt * 16 + lm;
            if (c >= PD2) continue;
            float bv = bias[c];
            float rc = router1 ? router1[c] : 0.f;
#pragma unroll
            for (int i = 0; i < 4; ++i) {
                int rr = row0 + wm * 32 + mt * 16 + lq * 4 + i;
                float v = acc[mt][nt][i] + bv;
                outFcol[(size_t)rr * FD + c] = v;
                fFbcol[(size_t)rr * FDP + c] = f2b(v);
                if (tgp1b) {
                    float ro = rou1[rr];
                    tgp1b[(size_t)rr * PD2P + c] =
                        f2b((v + ro * rc) / (1.f + ro + 1e-12f));
                }
            }
        }
}

// ---------------------------------------------------------------- q2 projection (K=776)
__global__ __launch_bounds__(256) void q2_gemm(
    const short* __restrict__ A, const short* __restrict__ B,
    const float* __restrict__ bias, short* __restrict__ outB)
{
    __shared__ __align__(16) short LDS[5120];
    short* Als = LDS;
    short* Bls = LDS + 64 * 40;
    const int tid = threadIdx.x;
    const int lane = tid & 63, wv = tid >> 6;
    const int wm = wv >> 1, wn = wv & 1;
    const int lm = lane & 15, lq = lane >> 4;
    const int row0 = blockIdx.y * 64, col0 = blockIdx.x * 64;
    const f32x4 zero4 = {0.f, 0.f, 0.f, 0.f};
    f32x4 acc[2][2] = {{zero4, zero4}, {zero4, zero4}};
    const s8v zero8 = {0, 0, 0, 0, 0, 0, 0, 0};
    const int r = tid >> 2, cgp = tid & 3;
    for (int k0 = 0; k0 < FDP; k0 += 32) {
        int gk = k0 + cgp * 8;
        s8v va = zero8, vb = zero8;
        if (gk < FDP) {
            va = *(const s8v*)(A + (size_t)(row0 + r) * FDP + gk);
            vb = *(const s8v*)(B + (size_t)(col0 + r) * FDP + gk);
        }
        *(s8v*)(Als + r * 40 + cgp * 8) = va;
        *(s8v*)(Bls + r * 40 + cgp * 8) = vb;
        __syncthreads();
        s8v af[2], bf[2];
#pragma unroll
        for (int mt = 0; mt < 2; ++mt)
            af[mt] = *(const s8v*)(Als + (wm * 32 + mt * 16 + lm) * 40 + lq * 8);
#pragma unroll
        for (int nt = 0; nt < 2; ++nt)
            bf[nt] = *(const s8v*)(Bls + (wn * 32 + nt * 16 + lm) * 40 + lq * 8);
#pragma unroll
        for (int mt = 0; mt < 2; ++mt)
#pragma unroll
            for (int nt = 0; nt < 2; ++nt)
                acc[mt][nt] = __builtin_amdgcn_mfma_f32_16x16x32_bf16(
                    af[mt], bf[nt], acc[mt][nt], 0, 0, 0);
        __syncthreads();
    }
    const float INV_TEMP = 0.08838834764831845f;
#pragma unroll
    for (int mt = 0; mt < 2; ++mt)
#pragma unroll
        for (int nt = 0; nt < 2; ++nt) {
            int c = col0 + wn * 32 + nt * 16 + lm;
            float bv = bias[c];
#pragma unroll
            for (int i = 0; i < 4; ++i) {
                int rr = row0 + wm * 32 + mt * 16 + lq * 4 + i;
                outB[(size_t)rr * DZ + c] = f2b(INV_TEMP * (acc[mt][nt][i] + bv));
            }
        }
}

// ---------------------------------------------------------------- attention 2
__global__ __launch_bounds__(256) void attn2_flash(
    const short* __restrict__ Q, const short* __restrict__ Kk,
    const float* __restrict__ V, float* __restrict__ part2)
{
    __shared__ __align__(16) short Qls[64 * 136];
    __shared__ __align__(16) short Kls[64 * 136];
    __shared__ float Vls[128];
    const int tid = threadIdx.x;
    const int lane = tid & 63, wv = tid >> 6;
    const int lm = lane & 15, lq = lane >> 4;
    const int chunk = blockIdx.x & 15, row0 = (blockIdx.x >> 4) * 64;
    const f32x4 zero4 = {0.f, 0.f, 0.f, 0.f};
#pragma unroll
    for (int l = 0; l < 4; ++l) {
        int id = l * 256 + tid;
        int r = id >> 4, g = id & 15;
        *(s8v*)(Qls + r * 136 + g * 8) = *(const s8v*)(Q + (size_t)(row0 + r) * DZ + g * 8);
    }
    __syncthreads();
    s8v af[4];
#pragma unroll
    for (int ks = 0; ks < 4; ++ks)
        af[ks] = *(const s8v*)(Qls + (wv * 16 + lm) * 136 + ks * 32 + lq * 8);
    float z[4] = {0.f, 0.f, 0.f, 0.f};
    float y0[4] = {0.f, 0.f, 0.f, 0.f};
    float y1[4] = {0.f, 0.f, 0.f, 0.f};
    for (int t = 0; t < 4; ++t) {
        int col0 = chunk * 256 + t * 64;
        __syncthreads();
#pragma unroll
        for (int l = 0; l < 4; ++l) {
            int id = l * 256 + tid;
            int r = id >> 4, g = id & 15;
            *(s8v*)(Kls + r * 136 + g * 8) =
                *(const s8v*)(Kk + (size_t)(col0 + r) * 256 + 128 + g * 8);
        }
        if (tid < 128) Vls[tid] = V[col0 * 2 + tid];
        __syncthreads();
        f32x4 acc[4];
#pragma unroll
        for (int nt = 0; nt < 4; ++nt) acc[nt] = zero4;
#pragma unroll
        for (int nt = 0; nt < 4; ++nt)
#pragma unroll
            for (int ks = 0; ks < 4; ++ks) {
                s8v bf = *(const s8v*)(Kls + (nt * 16 + lm) * 136 + ks * 32 + lq * 8);
                acc[nt] = __builtin_amdgcn_mfma_f32_16x16x32_bf16(af[ks], bf, acc[nt], 0, 0, 0);
            }
        float v0[4], v1[4];
#pragma unroll
        for (int nt = 0; nt < 4; ++nt) {
            v0[nt] = Vls[(nt * 16 + lm) * 2];
            v1[nt] = Vls[(nt * 16 + lm) * 2 + 1];
        }
#pragma unroll
        for (int i = 0; i < 4; ++i) {
            float e0 = __expf(acc[0][i]), e1 = __expf(acc[1][i]);
            float e2 = __expf(acc[2][i]), e3 = __expf(acc[3][i]);
            z[i]  += e0 + e1 + e2 + e3;
            y0[i] += e0 * v0[0] + e1 * v0[1] + e2 * v0[2] + e3 * v0[3];
            y1[i] += e0 * v1[0] + e1 * v1[1] + e2 * v1[2] + e3 * v1[3];
        }
    }
#pragma unroll
    for (int i = 0; i < 4; ++i) {
#pragma unroll
        for (int msk = 1; msk < 16; msk <<= 1) {
            z[i]  += __shfl_xor(z[i], msk, 64);
            y0[i] += __shfl_xor(y0[i], msk, 64);
            y1[i] += __shfl_xor(y1[i], msk, 64);
        }
    }
    if (lm == 0) {
#pragma unroll
        for (int i = 0; i < 4; ++i) {
            int r = row0 + wv * 16 + lq * 4 + i;
            float* pp = part2 + ((size_t)r * 16 + chunk) * 4;
            pp[0] = z[i]; pp[1] = y0[i]; pp[2] = y1[i];
        }
    }
}

__global__ void attn2_combine(const float* __restrict__ part2, float* __restrict__ out) {
    int r = blockIdx.x * 256 + threadIdx.x;
    if (r >= N2) return;
    const float* pp = part2 + (size_t)r * 64;
    float Zt = 0.f, Y0 = 0.f, Y1 = 0.f;
#pragma unroll
    for (int c = 0; c < 16; ++c) {
        Zt += pp[c * 4]; Y0 += pp[c * 4 + 1]; Y1 += pp[c * 4 + 2];
    }
    out[2 * r] = Y0 / Zt;
    out[2 * r + 1] = Y1 / Zt;
}

// ---------------------------------------------------------------- launch
extern "C" void kernel_launch(void* const* d_in, const int* in_sizes, int n_in,
                              void* d_out, int out_size, void* d_ws, size_t ws_size,
                              hipStream_t stream) {
    const float* lm_X = (const float*)d_in[0];
    const float* lm_Y = (const float*)d_in[1];
    const float* tg_X = (const float*)d_in[2];
    const float* lm_delay = (const float*)d_in[4];
    const float* tg_delay = (const float*)d_in[5];
    const float* aq_w = (const float*)d_in[6];
    const float* aq_b = (const float*)d_in[7];
    const float* ak_w = (const float*)d_in[8];
    const float* ak_b = (const float*)d_in[9];
    const float* w1_w = (const float*)d_in[10];
    const float* w1_b = (const float*)d_in[11];
    const float* w2_w = (const float*)d_in[12];
    const float* w2_b = (const float*)d_in[13];
    const float* pq_w = (const float*)d_in[14];
    const float* pq_b = (const float*)d_in[15];
    const float* pk_w = (const float*)d_in[16];
    const float* pk_b = (const float*)d_in[17];
    const float* pv_w = (const float*)d_in[18];
    const float* pv_b = (const float*)d_in[19];
    const float* g1 = (const float*)d_in[20];
    const float* g2 = (const float*)d_in[21];
    const float* g3 = (const float*)d_in[22];
    const float* al = (const float*)d_in[23];
    const float* be = (const float*)d_in[24];

    float* out = (float*)d_out;
    float* outF = out + (size_t)N2 * 2;

    char* base = (char*)d_ws;
    size_t off = 0;
    auto allocF = [&](size_t n) -> float* {
        float* q = (float*)(base + off);
        off += (n * 4 + 255) / 256 * 256;
        return q;
    };
    auto allocS = [&](size_t n) -> short* {
        short* q = (short*)(base + off);
        off += (n * 2 + 255) / 256 * 256;
        return q;
    };

    short* E        = allocS((size_t)N2 * N1);
    short* appart   = allocS((size_t)SPLITS * N2 * APN);
    short* lmFTb    = allocS((size_t)APN * N1);
    short* qb       = allocS((size_t)N2 * DZ);
    short* kk       = allocS((size_t)N1 * 256);
    short* q2       = allocS((size_t)N2 * DZ);
    short* tgp0b    = allocS((size_t)N2 * PD2P);
    short* tgp1b    = allocS((size_t)N2 * PD2P);
    short* finalFb  = allocS((size_t)N2 * FDP);
    short* w1wb     = allocS((size_t)PD2 * PD2P);
    short* w2wb     = allocS((size_t)PD2 * PD2P);
    short* pqwb     = allocS((size_t)DZ * FDP);
    float* v2b      = allocF((size_t)N1 * 2);
    float* part2    = allocF((size_t)N2 * 64);
    float* Zbuf     = allocF(N2);
    float* router0  = allocF(PD2);
    float* routerp0 = allocF(PD2);
    float* router1  = allocF(PD2);
    float* dscore   = allocF(N1);
    float* rou0     = allocF(N2);
    float* rou1     = allocF(N2);

    // 1. conversions / tiled lmFT transpose / zero-fills
    hipLaunchKernelGGL(cvt_all, dim3(GT + FLAT_BLOCKS), dim3(256), 0, stream,
                       lm_X, lm_Y, tg_X, pq_w, w1_w, w2_w,
                       lm_delay, tg_delay, g1, g2, g3, al, be, pv_w, pv_b,
                       w1wb, w2wb, pqwb, lmFTb,
                       dscore, rou0, rou1, v2b, Zbuf, finalFb, tgp1b, outF);
    // 2. router + kk + qb (one kernel, 578 blocks)
    hipLaunchKernelGGL(rkq_kernel, dim3(578), dim3(256), 0, stream,
                       lm_X, tg_X, aq_w, aq_b, ak_w, ak_b, pk_w, pk_b,
                       lmFTb, dscore, router0, routerp0, kk, qb);
    // 3. E = exp(scores), Z rowsums (+router1 block)
    hipLaunchKernelGGL(scores_e, dim3(513), dim3(256), 0, stream,
                       qb, kk, E, Zbuf, routerp0, w1_w, w1_b, router1);
    // 4. AP partials (bf16)
    hipLaunchKernelGGL(ap_gemm, dim3(256), dim3(512), 0, stream, E, Zbuf, lmFTb, appart);
    // 5. tgp0
    hipLaunchKernelGGL(fix_tgp0, dim3(N2), dim3(256), 0, stream,
                       appart, tg_X, rou0, router0, tgp0b);
    // 6. tf1 (+ fused tgp1)
    hipLaunchKernelGGL(w_gemm, dim3(5, 32), dim3(256), 0, stream,
                       tgp0b, w1wb, w1_b, outF + 256, finalFb + 256, rou1, router1, tgp1b);
    // 7. tf2
    hipLaunchKernelGGL(w_gemm, dim3(5, 32), dim3(256), 0, stream,
                       tgp1b, w2wb, w2_b, outF + 514, finalFb + 514,
                       nullptr, nullptr, nullptr);
    // 8. q2
    hipLaunchKernelGGL(q2_gemm, dim3(2, 32), dim3(256), 0, stream,
                       finalFb, pqwb, pq_b, q2);
    // 9-10. attention 2 + combine
    hipLaunchKernelGGL(attn2_flash, dim3(512), dim3(256), 0, stream,
                       q2, kk, v2b, part2);
    hipLaunchKernelGGL(attn2_combine, dim3(8), dim3(256), 0, stream, part2, out);
}